// Round 19
// baseline (259.613 us; speedup 1.0000x reference)
//
#include <hip/hip_runtime.h>
#include <math.h>
#include <stdint.h>

#define NROWS 4096
#define DIM   512
#define NCLS  64
#define CAP   128
#define PD    768
#define NL    3
#define PARTSZ (size_t)(NCLS * 4 * 1024)

typedef __attribute__((ext_vector_type(8))) short short8v;
typedef __attribute__((ext_vector_type(4))) float f32x4;

__device__ __forceinline__ unsigned short f2bf(float f) {
  unsigned u = __float_as_uint(f);
  unsigned r = (u + 0x7FFF + ((u >> 16) & 1)) >> 16;
  return (unsigned short)r;
}

__device__ __forceinline__ float bf2f(unsigned short u) {
  return __uint_as_float(((unsigned)u) << 16);
}

__device__ __forceinline__ float4 bf4tof4(ushort4 u) {
  float4 f;
  f.x = bf2f(u.x); f.y = bf2f(u.y); f.z = bf2f(u.z); f.w = bf2f(u.w);
  return f;
}

// async global->LDS, 16B per lane; LDS dest = uniform base + lane*16
__device__ __forceinline__ void gload_lds16(const void* g, void* l) {
  auto* lp = reinterpret_cast<__attribute__((address_space(3))) unsigned int*>(
      reinterpret_cast<uintptr_t>(l));
  const auto* gp = reinterpret_cast<const __attribute__((address_space(1))) unsigned int*>(
      reinterpret_cast<uintptr_t>(g));
  __builtin_amdgcn_global_load_lds(gp, lp, 16, 0, 0);
}

__device__ __forceinline__ float waveReduce(float v) {
#pragma unroll
  for (int o = 32; o > 0; o >>= 1) v += __shfl_down(v, o);
  return v;
}

__device__ __forceinline__ float blockReduce(float v) {
  __shared__ float sh[4];
  int lane = threadIdx.x & 63, wv = threadIdx.x >> 6;
  v = waveReduce(v);
  if (lane == 0) sh[wv] = v;
  __syncthreads();
  float t = 0.f;
  if (threadIdx.x == 0) {
    int nw = (blockDim.x + 63) >> 6;
    for (int i = 0; i < nw; ++i) t += sh[i];
  }
  return t;
}

// ---------------- parallel stable bucketing ----------------
__global__ __launch_bounds__(256) void k_hist(const int* __restrict__ labels, int* __restrict__ chunkCnt) {
  __shared__ int h[NCLS];
  int t = threadIdx.x;
  if (t < NCLS) h[t] = 0;
  __syncthreads();
  atomicAdd(&h[labels[blockIdx.x * 256 + t]], 1);
  __syncthreads();
  if (t < NCLS) chunkCnt[blockIdx.x * NCLS + t] = h[t];
}

__global__ void k_scan(const int* __restrict__ chunkCnt, int* __restrict__ cnt,
                       int* __restrict__ off, int* __restrict__ chunkBase, float* __restrict__ acc) {
  __shared__ int sc[NCLS];
  int c = threadIdx.x;  // 64 threads
  if (c < 8) acc[c] = 0.f;
  int tot = 0;
  for (int b = 0; b < 16; ++b) tot += chunkCnt[b * NCLS + c];
  cnt[c] = tot;
  sc[c] = tot;
  __syncthreads();
  if (c == 0) {
    int s = 0;
    for (int i = 0; i < NCLS; ++i) { int tv = sc[i]; sc[i] = s; s += tv; }
  }
  __syncthreads();
  int run = sc[c];
  off[c] = run;
  for (int b = 0; b < 16; ++b) { chunkBase[b * NCLS + c] = run; run += chunkCnt[b * NCLS + c]; }
  if (c == 0) off[NCLS] = NROWS;
}

__global__ __launch_bounds__(256) void k_scatter(const int* __restrict__ labels, const int* __restrict__ chunkBase,
                                                 int* __restrict__ perm, int* __restrict__ clsp) {
  __shared__ int lab[256];
  int t = threadIdx.x;
  int r = blockIdx.x * 256 + t;
  int c = labels[r];
  lab[t] = c;
  __syncthreads();
  int rank = 0;
  for (int j = 0; j < t; ++j) rank += (lab[j] == c);
  int pos = chunkBase[blockIdx.x * NCLS + c] + rank;
  perm[pos] = r;
  clsp[pos] = c;
}

// fused: y<NL -> gathered bf16 copy + row inverse norms (layer y); y==NL -> weight bf16 conversion + rnorm zero
__global__ __launch_bounds__(128) void k_prepw(const float* __restrict__ feats, const int* __restrict__ perm,
                                               unsigned short* __restrict__ Gpb, float* __restrict__ invn,
                                               const float4* __restrict__ fc1, const float4* __restrict__ fc2,
                                               const float4* __restrict__ proj,
                                               ushort4* __restrict__ w1, ushort4* __restrict__ w2,
                                               ushort4* __restrict__ pj, float* __restrict__ rnorm) {
  int y = blockIdx.y;
  if (y == NL) {
    const int nW = NL * DIM * DIM / 4;
    const int nP = PD * DIM / 4;
    int idx = blockIdx.x * 128 + threadIdx.x;
    const float4* src; ushort4* dst; int k;
    if (idx < nW) { src = fc1; dst = w1; k = idx; }
    else if (idx < 2 * nW) { src = fc2; dst = w2; k = idx - nW; }
    else if (idx < 2 * nW + nP) { src = proj; dst = pj; k = idx - 2 * nW; }
    else {
      int z = idx - (2 * nW + nP);
      if (z < NL * NROWS) rnorm[z] = 0.f;
      return;
    }
    float4 v = src[k];
    ushort4 o;
    o.x = f2bf(v.x); o.y = f2bf(v.y); o.z = f2bf(v.z); o.w = f2bf(v.w);
    dst[k] = o;
    return;
  }
  __shared__ float red[2];
  int l = y;
  const float* G = feats + (size_t)l * NROWS * DIM;
  unsigned short* Gp = Gpb + (size_t)l * NROWS * DIM;
  int row = blockIdx.x, t = threadIdx.x;
  const float4* src = (const float4*)(G + (size_t)perm[row] * DIM);
  float4 v = src[t];
  ushort4 b;
  b.x = f2bf(v.x); b.y = f2bf(v.y); b.z = f2bf(v.z); b.w = f2bf(v.w);
  *(ushort4*)(Gp + (size_t)row * DIM + t * 4) = b;
  float ss = v.x * v.x + v.y * v.y + v.z * v.z + v.w * v.w;
  ss = waveReduce(ss);
  if ((t & 63) == 0) red[t >> 6] = ss;
  __syncthreads();
  if (t == 0) invn[l * NROWS + row] = 1.f / fmaxf(sqrtf(red[0] + red[1]), 1e-12f);
}

// per-class cosine-sim via bf16 MFMA: 32x32 tile per block; z = layer
__global__ __launch_bounds__(256) void k_sim(const unsigned short* __restrict__ Gpb,
                                             const float* __restrict__ invn,
                                             const int* __restrict__ cnt, const int* __restrict__ off,
                                             float* __restrict__ sim) {
  int l = blockIdx.z;
  const unsigned short* Gp = Gpb + (size_t)l * NROWS * DIM;
  const float* inv = invn + (size_t)l * NROWS;
  float* sm = sim + (size_t)l * NCLS * CAP * CAP;
  int c = blockIdx.y;
  int n = min(cnt[c], CAP);
  int ti = blockIdx.x >> 2, tj = blockIdx.x & 3;
  if (ti * 32 >= n || tj * 32 >= n) return;
  int base = off[c];
  __shared__ short As[32][40];
  __shared__ short Bs[32][40];
  const int t = threadIdx.x;
  const int lane = t & 63, wv = t >> 6;
  const int qi = wv >> 1, qj = wv & 1;
  const int fr = lane & 15, kg = lane >> 4;
  const int half = t >> 7, tt = t & 127;
  const int srow = tt >> 2, scol = (tt & 3) * 8;
  int gr = (half ? tj : ti) * 32 + srow;
  const unsigned short* ps = Gp + (size_t)(base + min(gr, n - 1)) * DIM + scol;
  short* dst = half ? &Bs[srow][scol] : &As[srow][scol];
  f32x4 acc = {};
  for (int k0 = 0; k0 < DIM; k0 += 32) {
    short8v v = *(const short8v*)(ps + k0);
    __syncthreads();
    *(short8v*)dst = v;
    __syncthreads();
    short8v af = *(const short8v*)&As[qi * 16 + fr][kg * 8];
    short8v bf = *(const short8v*)&Bs[qj * 16 + fr][kg * 8];
    acc = __builtin_amdgcn_mfma_f32_16x16x32_bf16(af, bf, acc, 0, 0, 0);
  }
  int gj = tj * 32 + qj * 16 + fr;
  int r0 = ti * 32 + qi * 16 + kg * 4;
  if (gj < n) {
    float sj = inv[base + gj];
#pragma unroll
    for (int r = 0; r < 4; ++r) {
      int gi = r0 + r;
      if (gi < n) {
        float v = acc[r] * inv[base + gi] * sj;
        v = fminf(fmaxf(v, -1.0f + 1e-8f), 1.0f - 1e-8f);
        sm[((size_t)c * CAP + gi) * CAP + gj] = v;
      }
    }
  }
}

// top-8 per row within class (float4 scan, same j-ascending insertion); y = layer
__global__ __launch_bounds__(256) void k_topk(const float* __restrict__ sim, const int* __restrict__ cnt,
                                              const int* __restrict__ off, const int* __restrict__ clsp,
                                              int* __restrict__ t8) {
  int l = blockIdx.y;
  const float* sm = sim + (size_t)l * NCLS * CAP * CAP;
  int* t8l = t8 + (size_t)l * NROWS * 8;
  int pr = blockIdx.x * 256 + threadIdx.x;
  if (pr >= NROWS) return;
  int c = clsp[pr];
  int n = min(cnt[c], CAP);
  int loc = pr - off[c];
  const float4* row4 = (const float4*)(sm + ((size_t)c * CAP + loc) * CAP);
  float bv[8]; int bi[8];
#pragma unroll
  for (int q = 0; q < 8; ++q) { bv[q] = -3e38f; bi[q] = -1; }
  for (int j4 = 0; j4 < CAP / 4; ++j4) {
    if (j4 * 4 >= n) break;
    float4 v4 = row4[j4];
    float vv[4] = {v4.x, v4.y, v4.z, v4.w};
#pragma unroll
    for (int k = 0; k < 4; ++k) {
      int j = j4 * 4 + k;
      if (j >= n || j == loc) continue;
      float v = vv[k];
      if (v > bv[7]) {
        bv[7] = v; bi[7] = j;
#pragma unroll
        for (int q = 7; q > 0; --q) {
          if (bv[q] > bv[q - 1]) {
            float tv = bv[q]; bv[q] = bv[q - 1]; bv[q - 1] = tv;
            int tq = bi[q]; bi[q] = bi[q - 1]; bi[q - 1] = tq;
          }
        }
      }
    }
  }
#pragma unroll
  for (int q = 0; q < 8; ++q) t8l[pr * 8 + q] = bi[q];
}

// ---- build S pass 1: masked weights + row degree -> dinv; z = layer ----
__global__ __launch_bounds__(256) void k_buildS1(const float* __restrict__ sim, const int* __restrict__ cnt,
                                                 const int* __restrict__ off, const int* __restrict__ t8,
                                                 float* __restrict__ S, float* __restrict__ dinv) {
  int l = blockIdx.z;
  float alpha = 1.0f + 0.1f * l;
  const float* sm = sim + (size_t)l * NCLS * CAP * CAP;
  float* Sl = S + (size_t)l * NCLS * CAP * CAP;
  const int* t8l = t8 + (size_t)l * NROWS * 8;
  float* dv = dinv + (size_t)l * NCLS * CAP;
  int c = blockIdx.x;
  int n = min(cnt[c], CAP);
  int i0 = blockIdx.y * 32;
  if (i0 >= n) return;
  int base = off[c];
  __shared__ int sh8[CAP * 8];
  for (int i = threadIdx.x; i < n * 8; i += 256) sh8[i] = t8l[base * 8 + i];
  __syncthreads();
  int r = threadIdx.x >> 3;
  int lj = threadIdx.x & 7;
  int i = i0 + r;
  float d = 0.f;
  if (i < n) {
    int my8[8];
#pragma unroll
    for (int q = 0; q < 8; ++q) my8[q] = sh8[i * 8 + q];
    const float* srow = sm + ((size_t)c * CAP + i) * CAP;
    float* wrow = Sl + ((size_t)c * CAP + i) * CAP;
    for (int j = lj; j < n; j += 8) {
      float w;
      if (j == i) w = 1e-6f;
      else {
        bool m = false;
#pragma unroll
        for (int q = 0; q < 8; ++q) m = m || (my8[q] == j) || (sh8[j * 8 + q] == i);
        w = m ? alpha * fmaxf(srow[j], 0.f) : 0.f;
      }
      wrow[j] = w;
      d += w;
    }
  }
  d += __shfl_xor(d, 1);
  d += __shfl_xor(d, 2);
  d += __shfl_xor(d, 4);
  if (lj == 0 && i < n) dv[c * CAP + i] = 1.f / sqrtf(fmaxf(d, 1e-8f));
}

// ---- build S pass 2: S[i][j] *= dinv_i * dinv_j; z = layer ----
__global__ __launch_bounds__(256) void k_buildS2(float* __restrict__ S, const float* __restrict__ dinv,
                                                 const int* __restrict__ cnt) {
  int l = blockIdx.z;
  float* Sl = S + (size_t)l * NCLS * CAP * CAP;
  const float* dv = dinv + (size_t)l * NCLS * CAP;
  int c = blockIdx.x;
  int n = min(cnt[c], CAP);
  int i0 = blockIdx.y * 32;
  if (i0 >= n) return;
  __shared__ float sd[CAP];
  for (int k = threadIdx.x; k < n; k += 256) sd[k] = dv[c * CAP + k];
  __syncthreads();
  for (int p = threadIdx.x; p < 32 * CAP; p += 256) {
    int r = p >> 7, j = p & (CAP - 1);
    int i = i0 + r;
    if (i < n && j < n)
      Sl[((size_t)c * CAP + i) * CAP + j] *= sd[i] * sd[j];
  }
}

// ------------- bf16 MFMA GEMM: 128x64 tile, global_load_lds staging -------------
// out: fp32 C or bf16 Cb; optional fused row-sumsq (rnorm, from fp32 accumulators)
__global__ __launch_bounds__(256) void k_gemm_bf16(const short* __restrict__ A, const short* __restrict__ B,
                                                   float* __restrict__ C, unsigned short* __restrict__ Cb,
                                                   float* __restrict__ rnorm, int N,
                                                   long sA, long sB, long sC) {
  int l = blockIdx.z;
  A += (size_t)l * sA; B += (size_t)l * sB;
  if (Cb) Cb += (size_t)l * sC; else C += (size_t)l * sC;
  if (rnorm) rnorm += (size_t)l * NROWS;
  __shared__ __align__(16) short As[128][32];
  __shared__ __align__(16) short Bs[64][32];
  const int row0 = blockIdx.x * 128, col0 = blockIdx.y * 64;
  const int t = threadIdx.x;
  const int lane = t & 63, wv = t >> 6;
  const int fr = lane & 15, kg = lane >> 4;
  const int srow = lane >> 2, skb = (lane & 3) * 8;
  const short* pa = A + (size_t)(row0 + wv * 32 + srow) * DIM + skb;
  const short* pb = B + (size_t)(col0 + wv * 16 + srow) * DIM + skb;
  f32x4 acc[2][4] = {};
  for (int kt = 0; kt < DIM; kt += 32) {
    __syncthreads();
    gload_lds16(pa + kt, &As[wv * 32][0]);
    gload_lds16(pa + kt + (size_t)16 * DIM, &As[wv * 32 + 16][0]);
    gload_lds16(pb + kt, &Bs[wv * 16][0]);
    __syncthreads();
    short8v af[2], bf[4];
#pragma unroll
    for (int i = 0; i < 2; ++i) af[i] = *(const short8v*)&As[wv * 32 + i * 16 + fr][kg * 8];
#pragma unroll
    for (int j = 0; j < 4; ++j) bf[j] = *(const short8v*)&Bs[j * 16 + fr][kg * 8];
#pragma unroll
    for (int i = 0; i < 2; ++i)
#pragma unroll
      for (int j = 0; j < 4; ++j)
        acc[i][j] = __builtin_amdgcn_mfma_f32_16x16x32_bf16(af[i], bf[j], acc[i][j], 0, 0, 0);
  }
#pragma unroll
  for (int i = 0; i < 2; ++i) {
    int r0 = row0 + wv * 32 + i * 16 + kg * 4;
#pragma unroll
    for (int j = 0; j < 4; ++j) {
      int cc = col0 + j * 16 + fr;
#pragma unroll
      for (int r = 0; r < 4; ++r) {
        if (Cb) Cb[(size_t)(r0 + r) * N + cc] = f2bf(acc[i][j][r]);
        else C[(size_t)(r0 + r) * N + cc] = acc[i][j][r];
      }
    }
    if (rnorm) {
#pragma unroll
      for (int r = 0; r < 4; ++r) {
        float ss = acc[i][0][r] * acc[i][0][r] + acc[i][1][r] * acc[i][1][r] +
                   acc[i][2][r] * acc[i][2][r] + acc[i][3][r] * acc[i][3][r];
        ss += __shfl_xor(ss, 1);
        ss += __shfl_xor(ss, 2);
        ss += __shfl_xor(ss, 4);
        ss += __shfl_xor(ss, 8);
        if (fr == 0) atomicAdd(&rnorm[r0 + r], ss);
      }
    }
  }
}

// Y = S @ Xb (bf16 X) (+ optional bf16 residual Gb, class-sorted); z = layer*4 + rowchunk(32)
// thread: 8 rows x 4 cols; software-pipelined j-loop (bf16 loads, convert at use); CAP-stride staging
// optional fused column partial sums/sumsq (part != nullptr)
__global__ __launch_bounds__(256) void k_spmm32p(const float* __restrict__ S, const unsigned short* __restrict__ Xb,
                                                 const unsigned short* __restrict__ Gb,
                                                 float* __restrict__ Y, unsigned short* __restrict__ Yb,
                                                 float* __restrict__ part,
                                                 const int* __restrict__ cnt, const int* __restrict__ off) {
  int l = blockIdx.z >> 2;
  int zc = blockIdx.z & 3;
  const float* Sl = S + (size_t)l * NCLS * CAP * CAP;
  const ushort4* X4 = (const ushort4*)(Xb + (size_t)l * NROWS * DIM);
  const ushort4* Gb4 = Gb ? (const ushort4*)(Gb + (size_t)l * NROWS * DIM) : (const ushort4*)nullptr;
  float4* Y4 = Y ? (float4*)(Y + (size_t)l * NROWS * DIM) : (float4*)nullptr;
  ushort4* Yb4 = Yb ? (ushort4*)(Yb + (size_t)l * NROWS * DIM) : (ushort4*)nullptr;
  int c = blockIdx.x;
  int n = min(cnt[c], CAP);
  int i0 = zc * 32;
  float* pslot = part ? part + (size_t)l * PARTSZ + (size_t)(c * 4 + zc) * 1024 : (float*)nullptr;
  __shared__ float sS[32][CAP];
  if (i0 >= n) {
    if (pslot) {
      int col = blockIdx.y * 256 + threadIdx.x;
      pslot[col] = 0.f;
      pslot[512 + col] = 0.f;
    }
    return;
  }
  int base = off[c];
  int lane = threadIdx.x & 63;
  int col4 = blockIdx.y * 64 + lane;
  int ty = threadIdx.x >> 6;
  {
    const float4* S4 = (const float4*)(Sl + ((size_t)c * CAP + i0) * CAP);
    float4* sS4 = (float4*)&sS[0][0];
    for (int idx = threadIdx.x; idx < 32 * (CAP / 4); idx += 256) {
      int r = idx >> 5;
      sS4[idx] = (i0 + r < n) ? S4[idx] : make_float4(0.f, 0.f, 0.f, 0.f);
    }
  }
  __syncthreads();
  float4 acc[8];
#pragma unroll
  for (int ii = 0; ii < 8; ++ii) acc[ii] = make_float4(0.f, 0.f, 0.f, 0.f);
  size_t xbase = (size_t)base * 128 + col4;
  int n4 = n & ~3;
  ushort4 r0_, r1_, r2_, r3_;
  if (n4 > 0) {
    r0_ = X4[xbase];
    r1_ = X4[xbase + 128];
    r2_ = X4[xbase + 256];
    r3_ = X4[xbase + 384];
  }
  for (int j = 0; j < n4; j += 4) {
    ushort4 p0, p1, p2, p3;
    int jn = j + 4;
    if (jn < n4) {
      size_t b2 = xbase + (size_t)jn * 128;
      p0 = X4[b2];
      p1 = X4[b2 + 128];
      p2 = X4[b2 + 256];
      p3 = X4[b2 + 384];
    }
    float4 x0 = bf4tof4(r0_), x1 = bf4tof4(r1_), x2 = bf4tof4(r2_), x3 = bf4tof4(r3_);
#pragma unroll
    for (int ii = 0; ii < 8; ++ii) {
      float4 s4 = *(const float4*)&sS[ty * 8 + ii][j];
      acc[ii].x += s4.x * x0.x; acc[ii].y += s4.x * x0.y; acc[ii].z += s4.x * x0.z; acc[ii].w += s4.x * x0.w;
      acc[ii].x += s4.y * x1.x; acc[ii].y += s4.y * x1.y; acc[ii].z += s4.y * x1.z; acc[ii].w += s4.y * x1.w;
      acc[ii].x += s4.z * x2.x; acc[ii].y += s4.z * x2.y; acc[ii].z += s4.z * x2.z; acc[ii].w += s4.z * x2.w;
      acc[ii].x += s4.w * x3.x; acc[ii].y += s4.w * x3.y; acc[ii].z += s4.w * x3.z; acc[ii].w += s4.w * x3.w;
    }
    r0_ = p0; r1_ = p1; r2_ = p2; r3_ = p3;
  }
  for (int j = n4; j < n; ++j) {
    float4 x = bf4tof4(X4[xbase + (size_t)j * 128]);
#pragma unroll
    for (int ii = 0; ii < 8; ++ii) {
      float s = sS[ty * 8 + ii][j];
      acc[ii].x += s * x.x;
      acc[ii].y += s * x.y;
      acc[ii].z += s * x.z;
      acc[ii].w += s * x.w;
    }
  }
  float s1[4] = {0.f, 0.f, 0.f, 0.f}, s2[4] = {0.f, 0.f, 0.f, 0.f};
#pragma unroll
  for (int ii = 0; ii < 8; ++ii) {
    int r = i0 + ty * 8 + ii;
    if (r < n) {
      size_t o = (size_t)(base + r) * 128 + col4;
      float4 v = acc[ii];
      if (Gb4) {
        float4 g = bf4tof4(Gb4[o]);
        v.x += g.x; v.y += g.y; v.z += g.z; v.w += g.w;
      }
      if (pslot) {
        s1[0] += v.x; s1[1] += v.y; s1[2] += v.z; s1[3] += v.w;
        s2[0] += v.x * v.x; s2[1] += v.y * v.y; s2[2] += v.z * v.z; s2[3] += v.w * v.w;
      }
      if (Yb4) {
        ushort4 ob;
        ob.x = f2bf(v.x); ob.y = f2bf(v.y); ob.z = f2bf(v.z); ob.w = f2bf(v.w);
        Yb4[o] = ob;
      } else {
        Y4[o] = v;
      }
    }
  }
  if (pslot) {
    __syncthreads();
    float* scr = &sS[0][0];
#pragma unroll
    for (int q = 0; q < 4; ++q) {
      scr[(ty * 64 + lane) * 8 + q] = s1[q];
      scr[(ty * 64 + lane) * 8 + 4 + q] = s2[q];
    }
    __syncthreads();
    if (ty == 0) {
#pragma unroll
      for (int q = 0; q < 4; ++q) {
        float a = 0.f, b = 0.f;
#pragma unroll
        for (int g = 0; g < 4; ++g) {
          a += scr[(g * 64 + lane) * 8 + q];
          b += scr[(g * 64 + lane) * 8 + 4 + q];
        }
        int col = blockIdx.y * 256 + lane * 4 + q;
        pslot[col] = a;
        pslot[512 + col] = b;
      }
    }
  }
}

__global__ __launch_bounds__(64) void k_bnfin(const float* __restrict__ part, const float* __restrict__ gamma,
                                              const float* __restrict__ beta, float* __restrict__ sc) {
  int l = blockIdx.y;
  const float* pl = part + (size_t)l * PARTSZ;
  int k = blockIdx.x * 64 + threadIdx.x;
  float s = 0.f, s2 = 0.f;
  for (int b = 0; b < NCLS * 4; ++b) {
    s += pl[b * 1024 + k];
    s2 += pl[b * 1024 + 512 + k];
  }
  float m = s * (1.f / NROWS);
  float var = s2 * (1.f / NROWS) - m * m;
  float sg = gamma[l * DIM + k] / sqrtf(var + 1e-5f);
  sc[l * 2 * DIM + k] = sg;
  sc[l * 2 * DIM + DIM + k] = beta[l * DIM + k] - m * sg;
}

// BN+ReLU -> bf16; y = layer
__global__ __launch_bounds__(256) void k_bnrelu(const float4* __restrict__ X, const float* __restrict__ sc,
                                                ushort4* __restrict__ Yb) {
  int l = blockIdx.y;
  const float4* Xl = X + (size_t)l * (NROWS * DIM / 4);
  const float* scl = sc + (size_t)l * 2 * DIM;
  ushort4* Yl = Yb + (size_t)l * (NROWS * DIM / 4);
  int i = blockIdx.x * blockDim.x + threadIdx.x;
  int cb = (i * 4) & (DIM - 1);
  float4 v = Xl[i];
  ushort4 o;
  o.x = f2bf(fmaxf(v.x * scl[cb + 0] + scl[DIM + cb + 0], 0.f));
  o.y = f2bf(fmaxf(v.y * scl[cb + 1] + scl[DIM + cb + 1], 0.f));
  o.z = f2bf(fmaxf(v.z * scl[cb + 2] + scl[DIM + cb + 2], 0.f));
  o.w = f2bf(fmaxf(v.w * scl[cb + 3] + scl[DIM + cb + 3], 0.f));
  Yl[i] = o;
}

// merged losses: y in {0,1}: (S[y]-S[y+1])^2*cK ; y==2: (S[2]-SIGMA)^2*cI ;
// y in {3,4}: || l2norm(P[y-3]) - l2norm(P[y-2]) ||^2 * cZ  (P bf16, normalization via rnorm sumsq)
__global__ __launch_bounds__(256) void k_loss(const float* __restrict__ S, const unsigned short* __restrict__ P,
                                              const float* __restrict__ rnorm, const int* __restrict__ cnt,
                                              float target, float cK, float cI, float cZ,
                                              float* __restrict__ acc) {
  int y = blockIdx.y;
  if (y < 3) {
    if (blockIdx.x >= NCLS) return;
    const float* Sa = S + (size_t)y * NCLS * CAP * CAP;
    const float* Sb = nullptr;
    float coef;
    if (y < 2) { Sb = Sa + (size_t)NCLS * CAP * CAP; coef = cK; }
    else { Sa = S + (size_t)2 * NCLS * CAP * CAP; coef = cI; }
    int c = blockIdx.x;
    int n = min(cnt[c], CAP);
    float s = 0.f;
    for (int p = threadIdx.x; p < CAP * CAP; p += 256) {
      int i = p >> 7, j = p & (CAP - 1);
      if (i < n && j < n) {
        size_t o = ((size_t)c * CAP + i) * CAP + j;
        float d = Sb ? (Sa[o] - Sb[o]) : (Sa[o] - target);
        s += d * d;
      }
    }
    s = blockReduce(s);
    if (threadIdx.x == 0) atomicAdd(acc, s * coef);
  } else {
    int yy = y - 3;
    const unsigned short* A = P + (size_t)yy * NROWS * PD;
    const unsigned short* B = A + (size_t)NROWS * PD;
    const float* rnA = rnorm + (size_t)yy * NROWS;
    const float* rnB = rnA + NROWS;
    float s = 0.f;
    int row0 = blockIdx.x * 8;  // 512 blocks x 8 rows = 4096
#pragma unroll
    for (int ii = 0; ii < 8; ++ii) {
      int row = row0 + ii;
      float ia = 1.f / fmaxf(sqrtf(rnA[row]), 1e-12f);
      float ib = 1.f / fmaxf(sqrtf(rnB[row]), 1e-12f);
      const unsigned short* pa = A + (size_t)row * PD;
      const unsigned short* pb = B + (size_t)row * PD;
      for (int cidx = threadIdx.x; cidx < PD; cidx += 256) {
        float d = bf2f(pa[cidx]) * ia - bf2f(pb[cidx]) * ib;
        s += d * d;
      }
    }
    s = blockReduce(s);
    if (threadIdx.x == 0) atomicAdd(acc, s * cZ);
  }
}

__global__ void k_final(const float* __restrict__ acc, float* __restrict__ out) {
  if (threadIdx.x == 0) out[0] = acc[0];
}

// ---------------- host ----------------
extern "C" void kernel_launch(void* const* d_in, const int* in_sizes, int n_in,
                              void* d_out, int out_size, void* d_ws, size_t ws_size,
                              hipStream_t stream) {
  const float* feats = (const float*)d_in[0];
  const int* labels = (const int*)d_in[1];
  const float* fc1 = (const float*)d_in[2];
  const float* fc2 = (const float*)d_in[3];
  const float* gamma = (const float*)d_in[4];
  const float* beta = (const float*)d_in[5];
  const float* proj = (const float*)d_in[6];
  float* out = (float*)d_out;

  char* w = (char*)d_ws;
  auto alloc = [&](size_t bytes) { char* p = w; w += (bytes + 255) & ~(size_t)255; return p; };
  unsigned short* Xib = (unsigned short*)alloc((size_t)NL * NROWS * DIM * 2);  // T1b / T4b
  float* bufB = (float*)alloc((size_t)NL * NROWS * DIM * 4);                    // T2 fp32
  unsigned short* Gpb = (unsigned short*)alloc((size_t)NL * NROWS * DIM * 2);
  unsigned short* actb = (unsigned short*)alloc((size_t)NL * NROWS * DIM * 2);  // T3b then Zb
  unsigned short* W1b = (unsigned short*)alloc((size_t)NL * DIM * DIM * 2);
  unsigned short* W2b = (unsigned short*)alloc((size_t)NL * DIM * DIM * 2);
  unsigned short* Pjb = (unsigned short*)alloc((size_t)PD * DIM * 2);
  float* sim  = (float*)alloc((size_t)NL * NCLS * CAP * CAP * 4);
  float* S    = (float*)alloc((size_t)NL * NCLS * CAP * CAP * 4);
  unsigned short* Pb = (unsigned short*)alloc((size_t)NL * NROWS * PD * 2);
  float* invn = (float*)alloc((size_t)NL * NROWS * 4);
  float* dinv = (float*)alloc((size_t)NL * NCLS * CAP * 4);
  float* part = (float*)alloc((size_t)NL * PARTSZ * 4);
  float* bnsc = (float*)alloc((size_t)NL * 2 * DIM * 4);
  float* rnorm = (float*)alloc((size_t)NL * NROWS * 4);
  float* acc  = (float*)alloc(256);
  int* cnt  = (int*)alloc(NCLS * 4);
  int* offc = (int*)alloc((NCLS + 1) * 4);
  int* perm = (int*)alloc(NROWS * 4);
  int* clsp = (int*)alloc(NROWS * 4);
  int* t8   = (int*)alloc((size_t)NL * NROWS * 8 * 4);
  int* chunkCnt  = (int*)alloc(16 * NCLS * 4);
  int* chunkBase = (int*)alloc(16 * NCLS * 4);

  const float LAM_K = 64.f, LAM_Z = 16.f, SIGMA = 0.99f;
  const float cK = LAM_K / ((float)NROWS * (float)NROWS);
  const float cZ = LAM_Z / ((float)NROWS * (float)PD);
  const float cI = 1.f / ((float)NROWS * (float)NROWS);
  const long sAct = (long)NROWS * DIM;
  const long sW = (long)DIM * DIM;

  hipLaunchKernelGGL(k_hist, dim3(16), dim3(256), 0, stream, labels, chunkCnt);
  hipLaunchKernelGGL(k_scan, dim3(1), dim3(64), 0, stream, chunkCnt, cnt, offc, chunkBase, acc);
  hipLaunchKernelGGL(k_scatter, dim3(16), dim3(256), 0, stream, labels, chunkBase, perm, clsp);

  // fused prep (per-layer gather+bf16+invn), weight bf16 conversion, rnorm zero
  hipLaunchKernelGGL(k_prepw, dim3(NROWS, NL + 1), dim3(128), 0, stream, feats, perm, Gpb, invn,
                     (const float4*)fc1, (const float4*)fc2, (const float4*)proj,
                     (ushort4*)W1b, (ushort4*)W2b, (ushort4*)Pjb, rnorm);

  hipLaunchKernelGGL(k_sim, dim3(16, NCLS, NL), dim3(256), 0, stream, Gpb, invn, cnt, offc, sim);
  hipLaunchKernelGGL(k_topk, dim3(NROWS / 256, NL), dim3(256), 0, stream, sim, cnt, offc, clsp, t8);
  hipLaunchKernelGGL(k_buildS1, dim3(NCLS, CAP / 32, NL), dim3(256), 0, stream, sim, cnt, offc, t8, S, dinv);
  hipLaunchKernelGGL(k_buildS2, dim3(NCLS, CAP / 32, NL), dim3(256), 0, stream, S, dinv, cnt);

  // T1b = Gp @ w1^T (bf16 out)
  hipLaunchKernelGGL(k_gemm_bf16, dim3(NROWS / 128, DIM / 64, NL), dim3(256), 0, stream,
                     (const short*)Gpb, (const short*)W1b, (float*)nullptr, Xib, (float*)nullptr,
                     DIM, sAct, sW, (long)NROWS * DIM);
  // T2 = S @ T1b (fp32 out + fused BN column partial stats)
  hipLaunchKernelGGL(k_spmm32p, dim3(NCLS, DIM / 256, 4 * NL), dim3(256), 0, stream, S, Xib,
                     (const unsigned short*)nullptr, bufB, (unsigned short*)nullptr, part, cnt, offc);
  // BN finalize + relu -> bf16 T3
  hipLaunchKernelGGL(k_bnfin, dim3(DIM / 64, NL), dim3(64), 0, stream, part, gamma, beta, bnsc);
  hipLaunchKernelGGL(k_bnrelu, dim3(NROWS * DIM / 4 / 256, NL), dim3(256), 0, stream,
                     (const float4*)bufB, bnsc, (ushort4*)actb);
  // T4b = T3 @ w2^T (bf16 out)
  hipLaunchKernelGGL(k_gemm_bf16, dim3(NROWS / 128, DIM / 64, NL), dim3(256), 0, stream,
                     (const short*)actb, (const short*)W2b, (float*)nullptr, Xib, (float*)nullptr,
                     DIM, sAct, sW, (long)NROWS * DIM);
  // Z = S @ T4b + Gpb(bf16 residual) -> bf16 (actb)
  hipLaunchKernelGGL(k_spmm32p, dim3(NCLS, DIM / 256, 4 * NL), dim3(256), 0, stream, S, Xib,
                     Gpb, (float*)nullptr, actb, (float*)nullptr, cnt, offc);
  // P = Z @ proj^T (bf16 out, fused row-sumsq from fp32 acc into rnorm)
  hipLaunchKernelGGL(k_gemm_bf16, dim3(NROWS / 128, PD / 64, NL), dim3(256), 0, stream,
                     (const short*)actb, (const short*)Pjb, (float*)nullptr, Pb, rnorm,
                     PD, sAct, 0L, (long)NROWS * PD);

  // merged losses (P normalized on the fly)
  hipLaunchKernelGGL(k_loss, dim3(512, 5), dim3(256), 0, stream, S, Pb, rnorm, cnt, SIGMA, cK, cI, cZ, acc);

  hipLaunchKernelGGL(k_final, dim3(1), dim3(64), 0, stream, acc, out);
}

// Round 20
// 248.936 us; speedup vs baseline: 1.0429x; 1.0429x over previous
//
#include <hip/hip_runtime.h>
#include <math.h>
#include <stdint.h>

#define NROWS 4096
#define DIM   512
#define NCLS  64
#define CAP   128
#define PD    768
#define NL    3
#define PARTSZ (size_t)(NCLS * 4 * 1024)

typedef __attribute__((ext_vector_type(8))) short short8v;
typedef __attribute__((ext_vector_type(4))) float f32x4;

__device__ __forceinline__ unsigned short f2bf(float f) {
  unsigned u = __float_as_uint(f);
  unsigned r = (u + 0x7FFF + ((u >> 16) & 1)) >> 16;
  return (unsigned short)r;
}

__device__ __forceinline__ float bf2f(unsigned short u) {
  return __uint_as_float(((unsigned)u) << 16);
}

__device__ __forceinline__ float4 bf4tof4(ushort4 u) {
  float4 f;
  f.x = bf2f(u.x); f.y = bf2f(u.y); f.z = bf2f(u.z); f.w = bf2f(u.w);
  return f;
}

// async global->LDS, 16B per lane; LDS dest = uniform base + lane*16
__device__ __forceinline__ void gload_lds16(const void* g, void* l) {
  auto* lp = reinterpret_cast<__attribute__((address_space(3))) unsigned int*>(
      reinterpret_cast<uintptr_t>(l));
  const auto* gp = reinterpret_cast<const __attribute__((address_space(1))) unsigned int*>(
      reinterpret_cast<uintptr_t>(g));
  __builtin_amdgcn_global_load_lds(gp, lp, 16, 0, 0);
}

__device__ __forceinline__ float waveReduce(float v) {
#pragma unroll
  for (int o = 32; o > 0; o >>= 1) v += __shfl_down(v, o);
  return v;
}

__device__ __forceinline__ float blockReduce(float v) {
  __shared__ float sh[4];
  int lane = threadIdx.x & 63, wv = threadIdx.x >> 6;
  v = waveReduce(v);
  if (lane == 0) sh[wv] = v;
  __syncthreads();
  float t = 0.f;
  if (threadIdx.x == 0) {
    int nw = (blockDim.x + 63) >> 6;
    for (int i = 0; i < nw; ++i) t += sh[i];
  }
  return t;
}

// ---------------- parallel stable bucketing ----------------
__global__ __launch_bounds__(256) void k_hist(const int* __restrict__ labels, int* __restrict__ chunkCnt) {
  __shared__ int h[NCLS];
  int t = threadIdx.x;
  if (t < NCLS) h[t] = 0;
  __syncthreads();
  atomicAdd(&h[labels[blockIdx.x * 256 + t]], 1);
  __syncthreads();
  if (t < NCLS) chunkCnt[blockIdx.x * NCLS + t] = h[t];
}

__global__ void k_scan(const int* __restrict__ chunkCnt, int* __restrict__ cnt,
                       int* __restrict__ off, int* __restrict__ chunkBase, float* __restrict__ acc) {
  __shared__ int sc[NCLS];
  int c = threadIdx.x;  // 64 threads
  if (c < 8) acc[c] = 0.f;
  int tot = 0;
  for (int b = 0; b < 16; ++b) tot += chunkCnt[b * NCLS + c];
  cnt[c] = tot;
  sc[c] = tot;
  __syncthreads();
  if (c == 0) {
    int s = 0;
    for (int i = 0; i < NCLS; ++i) { int tv = sc[i]; sc[i] = s; s += tv; }
  }
  __syncthreads();
  int run = sc[c];
  off[c] = run;
  for (int b = 0; b < 16; ++b) { chunkBase[b * NCLS + c] = run; run += chunkCnt[b * NCLS + c]; }
  if (c == 0) off[NCLS] = NROWS;
}

__global__ __launch_bounds__(256) void k_scatter(const int* __restrict__ labels, const int* __restrict__ chunkBase,
                                                 int* __restrict__ perm, int* __restrict__ clsp) {
  __shared__ int lab[256];
  int t = threadIdx.x;
  int r = blockIdx.x * 256 + t;
  int c = labels[r];
  lab[t] = c;
  __syncthreads();
  int rank = 0;
  for (int j = 0; j < t; ++j) rank += (lab[j] == c);
  int pos = chunkBase[blockIdx.x * NCLS + c] + rank;
  perm[pos] = r;
  clsp[pos] = c;
}

// fused: y<NL -> gathered bf16 copy + row inverse norms (layer y); y==NL -> weight bf16 conversion + rnorm zero
__global__ __launch_bounds__(128) void k_prepw(const float* __restrict__ feats, const int* __restrict__ perm,
                                               unsigned short* __restrict__ Gpb, float* __restrict__ invn,
                                               const float4* __restrict__ fc1, const float4* __restrict__ fc2,
                                               const float4* __restrict__ proj,
                                               ushort4* __restrict__ w1, ushort4* __restrict__ w2,
                                               ushort4* __restrict__ pj, float* __restrict__ rnorm) {
  int y = blockIdx.y;
  if (y == NL) {
    const int nW = NL * DIM * DIM / 4;
    const int nP = PD * DIM / 4;
    int idx = blockIdx.x * 128 + threadIdx.x;
    const float4* src; ushort4* dst; int k;
    if (idx < nW) { src = fc1; dst = w1; k = idx; }
    else if (idx < 2 * nW) { src = fc2; dst = w2; k = idx - nW; }
    else if (idx < 2 * nW + nP) { src = proj; dst = pj; k = idx - 2 * nW; }
    else {
      int z = idx - (2 * nW + nP);
      if (z < NL * NROWS) rnorm[z] = 0.f;
      return;
    }
    float4 v = src[k];
    ushort4 o;
    o.x = f2bf(v.x); o.y = f2bf(v.y); o.z = f2bf(v.z); o.w = f2bf(v.w);
    dst[k] = o;
    return;
  }
  __shared__ float red[2];
  int l = y;
  const float* G = feats + (size_t)l * NROWS * DIM;
  unsigned short* Gp = Gpb + (size_t)l * NROWS * DIM;
  int row = blockIdx.x, t = threadIdx.x;
  const float4* src = (const float4*)(G + (size_t)perm[row] * DIM);
  float4 v = src[t];
  ushort4 b;
  b.x = f2bf(v.x); b.y = f2bf(v.y); b.z = f2bf(v.z); b.w = f2bf(v.w);
  *(ushort4*)(Gp + (size_t)row * DIM + t * 4) = b;
  float ss = v.x * v.x + v.y * v.y + v.z * v.z + v.w * v.w;
  ss = waveReduce(ss);
  if ((t & 63) == 0) red[t >> 6] = ss;
  __syncthreads();
  if (t == 0) invn[l * NROWS + row] = 1.f / fmaxf(sqrtf(red[0] + red[1]), 1e-12f);
}

// per-class cosine-sim via bf16 MFMA: 32x32 tile per block; z = layer
__global__ __launch_bounds__(256) void k_sim(const unsigned short* __restrict__ Gpb,
                                             const float* __restrict__ invn,
                                             const int* __restrict__ cnt, const int* __restrict__ off,
                                             float* __restrict__ sim) {
  int l = blockIdx.z;
  const unsigned short* Gp = Gpb + (size_t)l * NROWS * DIM;
  const float* inv = invn + (size_t)l * NROWS;
  float* sm = sim + (size_t)l * NCLS * CAP * CAP;
  int c = blockIdx.y;
  int n = min(cnt[c], CAP);
  int ti = blockIdx.x >> 2, tj = blockIdx.x & 3;
  if (ti * 32 >= n || tj * 32 >= n) return;
  int base = off[c];
  __shared__ short As[32][40];
  __shared__ short Bs[32][40];
  const int t = threadIdx.x;
  const int lane = t & 63, wv = t >> 6;
  const int qi = wv >> 1, qj = wv & 1;
  const int fr = lane & 15, kg = lane >> 4;
  const int half = t >> 7, tt = t & 127;
  const int srow = tt >> 2, scol = (tt & 3) * 8;
  int gr = (half ? tj : ti) * 32 + srow;
  const unsigned short* ps = Gp + (size_t)(base + min(gr, n - 1)) * DIM + scol;
  short* dst = half ? &Bs[srow][scol] : &As[srow][scol];
  f32x4 acc = {};
  for (int k0 = 0; k0 < DIM; k0 += 32) {
    short8v v = *(const short8v*)(ps + k0);
    __syncthreads();
    *(short8v*)dst = v;
    __syncthreads();
    short8v af = *(const short8v*)&As[qi * 16 + fr][kg * 8];
    short8v bf = *(const short8v*)&Bs[qj * 16 + fr][kg * 8];
    acc = __builtin_amdgcn_mfma_f32_16x16x32_bf16(af, bf, acc, 0, 0, 0);
  }
  int gj = tj * 32 + qj * 16 + fr;
  int r0 = ti * 32 + qi * 16 + kg * 4;
  if (gj < n) {
    float sj = inv[base + gj];
#pragma unroll
    for (int r = 0; r < 4; ++r) {
      int gi = r0 + r;
      if (gi < n) {
        float v = acc[r] * inv[base + gi] * sj;
        v = fminf(fmaxf(v, -1.0f + 1e-8f), 1.0f - 1e-8f);
        sm[((size_t)c * CAP + gi) * CAP + gj] = v;
      }
    }
  }
}

// top-8 per row within class (float4 scan, same j-ascending insertion); y = layer
__global__ __launch_bounds__(256) void k_topk(const float* __restrict__ sim, const int* __restrict__ cnt,
                                              const int* __restrict__ off, const int* __restrict__ clsp,
                                              int* __restrict__ t8) {
  int l = blockIdx.y;
  const float* sm = sim + (size_t)l * NCLS * CAP * CAP;
  int* t8l = t8 + (size_t)l * NROWS * 8;
  int pr = blockIdx.x * 256 + threadIdx.x;
  if (pr >= NROWS) return;
  int c = clsp[pr];
  int n = min(cnt[c], CAP);
  int loc = pr - off[c];
  const float4* row4 = (const float4*)(sm + ((size_t)c * CAP + loc) * CAP);
  float bv[8]; int bi[8];
#pragma unroll
  for (int q = 0; q < 8; ++q) { bv[q] = -3e38f; bi[q] = -1; }
  for (int j4 = 0; j4 < CAP / 4; ++j4) {
    if (j4 * 4 >= n) break;
    float4 v4 = row4[j4];
    float vv[4] = {v4.x, v4.y, v4.z, v4.w};
#pragma unroll
    for (int k = 0; k < 4; ++k) {
      int j = j4 * 4 + k;
      if (j >= n || j == loc) continue;
      float v = vv[k];
      if (v > bv[7]) {
        bv[7] = v; bi[7] = j;
#pragma unroll
        for (int q = 7; q > 0; --q) {
          if (bv[q] > bv[q - 1]) {
            float tv = bv[q]; bv[q] = bv[q - 1]; bv[q - 1] = tv;
            int tq = bi[q]; bi[q] = bi[q - 1]; bi[q - 1] = tq;
          }
        }
      }
    }
  }
#pragma unroll
  for (int q = 0; q < 8; ++q) t8l[pr * 8 + q] = bi[q];
}

// ---- build S pass 1: masked weights + row degree -> dinv; z = layer ----
__global__ __launch_bounds__(256) void k_buildS1(const float* __restrict__ sim, const int* __restrict__ cnt,
                                                 const int* __restrict__ off, const int* __restrict__ t8,
                                                 float* __restrict__ S, float* __restrict__ dinv) {
  int l = blockIdx.z;
  float alpha = 1.0f + 0.1f * l;
  const float* sm = sim + (size_t)l * NCLS * CAP * CAP;
  float* Sl = S + (size_t)l * NCLS * CAP * CAP;
  const int* t8l = t8 + (size_t)l * NROWS * 8;
  float* dv = dinv + (size_t)l * NCLS * CAP;
  int c = blockIdx.x;
  int n = min(cnt[c], CAP);
  int i0 = blockIdx.y * 32;
  if (i0 >= n) return;
  int base = off[c];
  __shared__ int sh8[CAP * 8];
  for (int i = threadIdx.x; i < n * 8; i += 256) sh8[i] = t8l[base * 8 + i];
  __syncthreads();
  int r = threadIdx.x >> 3;
  int lj = threadIdx.x & 7;
  int i = i0 + r;
  float d = 0.f;
  if (i < n) {
    int my8[8];
#pragma unroll
    for (int q = 0; q < 8; ++q) my8[q] = sh8[i * 8 + q];
    const float* srow = sm + ((size_t)c * CAP + i) * CAP;
    float* wrow = Sl + ((size_t)c * CAP + i) * CAP;
    for (int j = lj; j < n; j += 8) {
      float w;
      if (j == i) w = 1e-6f;
      else {
        bool m = false;
#pragma unroll
        for (int q = 0; q < 8; ++q) m = m || (my8[q] == j) || (sh8[j * 8 + q] == i);
        w = m ? alpha * fmaxf(srow[j], 0.f) : 0.f;
      }
      wrow[j] = w;
      d += w;
    }
  }
  d += __shfl_xor(d, 1);
  d += __shfl_xor(d, 2);
  d += __shfl_xor(d, 4);
  if (lj == 0 && i < n) dv[c * CAP + i] = 1.f / sqrtf(fmaxf(d, 1e-8f));
}

// ---- build S pass 2: S[i][j] *= dinv_i * dinv_j; z = layer ----
__global__ __launch_bounds__(256) void k_buildS2(float* __restrict__ S, const float* __restrict__ dinv,
                                                 const int* __restrict__ cnt) {
  int l = blockIdx.z;
  float* Sl = S + (size_t)l * NCLS * CAP * CAP;
  const float* dv = dinv + (size_t)l * NCLS * CAP;
  int c = blockIdx.x;
  int n = min(cnt[c], CAP);
  int i0 = blockIdx.y * 32;
  if (i0 >= n) return;
  __shared__ float sd[CAP];
  for (int k = threadIdx.x; k < n; k += 256) sd[k] = dv[c * CAP + k];
  __syncthreads();
  for (int p = threadIdx.x; p < 32 * CAP; p += 256) {
    int r = p >> 7, j = p & (CAP - 1);
    int i = i0 + r;
    if (i < n && j < n)
      Sl[((size_t)c * CAP + i) * CAP + j] *= sd[i] * sd[j];
  }
}

// ------------- bf16 MFMA GEMM: 128x64 tile, global_load_lds staging -------------
// out: fp32 C or bf16 Cb; optional fused row-sumsq (rnorm, from fp32 accumulators)
__global__ __launch_bounds__(256) void k_gemm_bf16(const short* __restrict__ A, const short* __restrict__ B,
                                                   float* __restrict__ C, unsigned short* __restrict__ Cb,
                                                   float* __restrict__ rnorm, int N,
                                                   long sA, long sB, long sC) {
  int l = blockIdx.z;
  A += (size_t)l * sA; B += (size_t)l * sB;
  if (Cb) Cb += (size_t)l * sC; else C += (size_t)l * sC;
  if (rnorm) rnorm += (size_t)l * NROWS;
  __shared__ __align__(16) short As[128][32];
  __shared__ __align__(16) short Bs[64][32];
  const int row0 = blockIdx.x * 128, col0 = blockIdx.y * 64;
  const int t = threadIdx.x;
  const int lane = t & 63, wv = t >> 6;
  const int fr = lane & 15, kg = lane >> 4;
  const int srow = lane >> 2, skb = (lane & 3) * 8;
  const short* pa = A + (size_t)(row0 + wv * 32 + srow) * DIM + skb;
  const short* pb = B + (size_t)(col0 + wv * 16 + srow) * DIM + skb;
  f32x4 acc[2][4] = {};
  for (int kt = 0; kt < DIM; kt += 32) {
    __syncthreads();
    gload_lds16(pa + kt, &As[wv * 32][0]);
    gload_lds16(pa + kt + (size_t)16 * DIM, &As[wv * 32 + 16][0]);
    gload_lds16(pb + kt, &Bs[wv * 16][0]);
    __syncthreads();
    short8v af[2], bf[4];
#pragma unroll
    for (int i = 0; i < 2; ++i) af[i] = *(const short8v*)&As[wv * 32 + i * 16 + fr][kg * 8];
#pragma unroll
    for (int j = 0; j < 4; ++j) bf[j] = *(const short8v*)&Bs[j * 16 + fr][kg * 8];
#pragma unroll
    for (int i = 0; i < 2; ++i)
#pragma unroll
      for (int j = 0; j < 4; ++j)
        acc[i][j] = __builtin_amdgcn_mfma_f32_16x16x32_bf16(af[i], bf[j], acc[i][j], 0, 0, 0);
  }
#pragma unroll
  for (int i = 0; i < 2; ++i) {
    int r0 = row0 + wv * 32 + i * 16 + kg * 4;
#pragma unroll
    for (int j = 0; j < 4; ++j) {
      int cc = col0 + j * 16 + fr;
#pragma unroll
      for (int r = 0; r < 4; ++r) {
        if (Cb) Cb[(size_t)(r0 + r) * N + cc] = f2bf(acc[i][j][r]);
        else C[(size_t)(r0 + r) * N + cc] = acc[i][j][r];
      }
    }
    if (rnorm) {
#pragma unroll
      for (int r = 0; r < 4; ++r) {
        float ss = acc[i][0][r] * acc[i][0][r] + acc[i][1][r] * acc[i][1][r] +
                   acc[i][2][r] * acc[i][2][r] + acc[i][3][r] * acc[i][3][r];
        ss += __shfl_xor(ss, 1);
        ss += __shfl_xor(ss, 2);
        ss += __shfl_xor(ss, 4);
        ss += __shfl_xor(ss, 8);
        if (fr == 0) atomicAdd(&rnorm[r0 + r], ss);
      }
    }
  }
}

// Y = S @ X (+ optional bf16 residual Gb, already class-sorted); z = layer*4 + rowchunk(32)
// thread: 8 rows x 4 cols (float4); software-pipelined j-loop; CAP-stride float4 staging
// optional fused column partial sums/sumsq (part != nullptr)
__global__ __launch_bounds__(256) void k_spmm32p(const float* __restrict__ S, const float* __restrict__ X,
                                                 const unsigned short* __restrict__ Gb,
                                                 float* __restrict__ Y, unsigned short* __restrict__ Yb,
                                                 float* __restrict__ part,
                                                 const int* __restrict__ cnt, const int* __restrict__ off) {
  int l = blockIdx.z >> 2;
  int zc = blockIdx.z & 3;
  const float* Sl = S + (size_t)l * NCLS * CAP * CAP;
  const float4* X4 = (const float4*)(X + (size_t)l * NROWS * DIM);
  const ushort4* Gb4 = Gb ? (const ushort4*)(Gb + (size_t)l * NROWS * DIM) : (const ushort4*)nullptr;
  float4* Y4 = Y ? (float4*)(Y + (size_t)l * NROWS * DIM) : (float4*)nullptr;
  ushort4* Yb4 = Yb ? (ushort4*)(Yb + (size_t)l * NROWS * DIM) : (ushort4*)nullptr;
  int c = blockIdx.x;
  int n = min(cnt[c], CAP);
  int i0 = zc * 32;
  float* pslot = part ? part + (size_t)l * PARTSZ + (size_t)(c * 4 + zc) * 1024 : (float*)nullptr;
  __shared__ float sS[32][CAP];
  if (i0 >= n) {
    if (pslot) {
      int col = blockIdx.y * 256 + threadIdx.x;
      pslot[col] = 0.f;
      pslot[512 + col] = 0.f;
    }
    return;
  }
  int base = off[c];
  int lane = threadIdx.x & 63;
  int col4 = blockIdx.y * 64 + lane;
  int ty = threadIdx.x >> 6;
  {
    const float4* S4 = (const float4*)(Sl + ((size_t)c * CAP + i0) * CAP);
    float4* sS4 = (float4*)&sS[0][0];
    for (int idx = threadIdx.x; idx < 32 * (CAP / 4); idx += 256) {
      int r = idx >> 5;
      sS4[idx] = (i0 + r < n) ? S4[idx] : make_float4(0.f, 0.f, 0.f, 0.f);
    }
  }
  __syncthreads();
  float4 acc[8];
#pragma unroll
  for (int ii = 0; ii < 8; ++ii) acc[ii] = make_float4(0.f, 0.f, 0.f, 0.f);
  size_t xbase = (size_t)base * 128 + col4;
  int n4 = n & ~3;
  float4 x0, x1, x2, x3;
  if (n4 > 0) {
    x0 = X4[xbase];
    x1 = X4[xbase + 128];
    x2 = X4[xbase + 256];
    x3 = X4[xbase + 384];
  }
  for (int j = 0; j < n4; j += 4) {
    float4 nx0, nx1, nx2, nx3;
    int jn = j + 4;
    if (jn < n4) {
      size_t b2 = xbase + (size_t)jn * 128;
      nx0 = X4[b2];
      nx1 = X4[b2 + 128];
      nx2 = X4[b2 + 256];
      nx3 = X4[b2 + 384];
    }
#pragma unroll
    for (int ii = 0; ii < 8; ++ii) {
      float4 s4 = *(const float4*)&sS[ty * 8 + ii][j];
      acc[ii].x += s4.x * x0.x; acc[ii].y += s4.x * x0.y; acc[ii].z += s4.x * x0.z; acc[ii].w += s4.x * x0.w;
      acc[ii].x += s4.y * x1.x; acc[ii].y += s4.y * x1.y; acc[ii].z += s4.y * x1.z; acc[ii].w += s4.y * x1.w;
      acc[ii].x += s4.z * x2.x; acc[ii].y += s4.z * x2.y; acc[ii].z += s4.z * x2.z; acc[ii].w += s4.z * x2.w;
      acc[ii].x += s4.w * x3.x; acc[ii].y += s4.w * x3.y; acc[ii].z += s4.w * x3.z; acc[ii].w += s4.w * x3.w;
    }
    x0 = nx0; x1 = nx1; x2 = nx2; x3 = nx3;
  }
  for (int j = n4; j < n; ++j) {
    float4 x = X4[xbase + (size_t)j * 128];
#pragma unroll
    for (int ii = 0; ii < 8; ++ii) {
      float s = sS[ty * 8 + ii][j];
      acc[ii].x += s * x.x;
      acc[ii].y += s * x.y;
      acc[ii].z += s * x.z;
      acc[ii].w += s * x.w;
    }
  }
  float s1[4] = {0.f, 0.f, 0.f, 0.f}, s2[4] = {0.f, 0.f, 0.f, 0.f};
#pragma unroll
  for (int ii = 0; ii < 8; ++ii) {
    int r = i0 + ty * 8 + ii;
    if (r < n) {
      size_t o = (size_t)(base + r) * 128 + col4;
      float4 v = acc[ii];
      if (Gb4) {
        float4 g = bf4tof4(Gb4[o]);
        v.x += g.x; v.y += g.y; v.z += g.z; v.w += g.w;
      }
      if (pslot) {
        s1[0] += v.x; s1[1] += v.y; s1[2] += v.z; s1[3] += v.w;
        s2[0] += v.x * v.x; s2[1] += v.y * v.y; s2[2] += v.z * v.z; s2[3] += v.w * v.w;
      }
      if (Yb4) {
        ushort4 ob;
        ob.x = f2bf(v.x); ob.y = f2bf(v.y); ob.z = f2bf(v.z); ob.w = f2bf(v.w);
        Yb4[o] = ob;
      } else {
        Y4[o] = v;
      }
    }
  }
  if (pslot) {
    __syncthreads();
    float* scr = &sS[0][0];
#pragma unroll
    for (int q = 0; q < 4; ++q) {
      scr[(ty * 64 + lane) * 8 + q] = s1[q];
      scr[(ty * 64 + lane) * 8 + 4 + q] = s2[q];
    }
    __syncthreads();
    if (ty == 0) {
#pragma unroll
      for (int q = 0; q < 4; ++q) {
        float a = 0.f, b = 0.f;
#pragma unroll
        for (int g = 0; g < 4; ++g) {
          a += scr[(g * 64 + lane) * 8 + q];
          b += scr[(g * 64 + lane) * 8 + 4 + q];
        }
        int col = blockIdx.y * 256 + lane * 4 + q;
        pslot[col] = a;
        pslot[512 + col] = b;
      }
    }
  }
}

__global__ __launch_bounds__(64) void k_bnfin(const float* __restrict__ part, const float* __restrict__ gamma,
                                              const float* __restrict__ beta, float* __restrict__ sc) {
  int l = blockIdx.y;
  const float* pl = part + (size_t)l * PARTSZ;
  int k = blockIdx.x * 64 + threadIdx.x;
  float s = 0.f, s2 = 0.f;
  for (int b = 0; b < NCLS * 4; ++b) {
    s += pl[b * 1024 + k];
    s2 += pl[b * 1024 + 512 + k];
  }
  float m = s * (1.f / NROWS);
  float var = s2 * (1.f / NROWS) - m * m;
  float sg = gamma[l * DIM + k] / sqrtf(var + 1e-5f);
  sc[l * 2 * DIM + k] = sg;
  sc[l * 2 * DIM + DIM + k] = beta[l * DIM + k] - m * sg;
}

// BN+ReLU -> bf16; y = layer
__global__ __launch_bounds__(256) void k_bnrelu(const float4* __restrict__ X, const float* __restrict__ sc,
                                                ushort4* __restrict__ Yb) {
  int l = blockIdx.y;
  const float4* Xl = X + (size_t)l * (NROWS * DIM / 4);
  const float* scl = sc + (size_t)l * 2 * DIM;
  ushort4* Yl = Yb + (size_t)l * (NROWS * DIM / 4);
  int i = blockIdx.x * blockDim.x + threadIdx.x;
  int cb = (i * 4) & (DIM - 1);
  float4 v = Xl[i];
  ushort4 o;
  o.x = f2bf(fmaxf(v.x * scl[cb + 0] + scl[DIM + cb + 0], 0.f));
  o.y = f2bf(fmaxf(v.y * scl[cb + 1] + scl[DIM + cb + 1], 0.f));
  o.z = f2bf(fmaxf(v.z * scl[cb + 2] + scl[DIM + cb + 2], 0.f));
  o.w = f2bf(fmaxf(v.w * scl[cb + 3] + scl[DIM + cb + 3], 0.f));
  Yl[i] = o;
}

// merged losses: y in {0,1}: (S[y]-S[y+1])^2*cK ; y==2: (S[2]-SIGMA)^2*cI ;
// y in {3,4}: || l2norm(P[y-3]) - l2norm(P[y-2]) ||^2 * cZ  (P bf16, normalization via rnorm sumsq)
__global__ __launch_bounds__(256) void k_loss(const float* __restrict__ S, const unsigned short* __restrict__ P,
                                              const float* __restrict__ rnorm, const int* __restrict__ cnt,
                                              float target, float cK, float cI, float cZ,
                                              float* __restrict__ acc) {
  int y = blockIdx.y;
  if (y < 3) {
    if (blockIdx.x >= NCLS) return;
    const float* Sa = S + (size_t)y * NCLS * CAP * CAP;
    const float* Sb = nullptr;
    float coef;
    if (y < 2) { Sb = Sa + (size_t)NCLS * CAP * CAP; coef = cK; }
    else { Sa = S + (size_t)2 * NCLS * CAP * CAP; coef = cI; }
    int c = blockIdx.x;
    int n = min(cnt[c], CAP);
    float s = 0.f;
    for (int p = threadIdx.x; p < CAP * CAP; p += 256) {
      int i = p >> 7, j = p & (CAP - 1);
      if (i < n && j < n) {
        size_t o = ((size_t)c * CAP + i) * CAP + j;
        float d = Sb ? (Sa[o] - Sb[o]) : (Sa[o] - target);
        s += d * d;
      }
    }
    s = blockReduce(s);
    if (threadIdx.x == 0) atomicAdd(acc, s * coef);
  } else {
    int yy = y - 3;
    const unsigned short* A = P + (size_t)yy * NROWS * PD;
    const unsigned short* B = A + (size_t)NROWS * PD;
    const float* rnA = rnorm + (size_t)yy * NROWS;
    const float* rnB = rnA + NROWS;
    float s = 0.f;
    int row0 = blockIdx.x * 8;  // 512 blocks x 8 rows = 4096
#pragma unroll
    for (int ii = 0; ii < 8; ++ii) {
      int row = row0 + ii;
      float ia = 1.f / fmaxf(sqrtf(rnA[row]), 1e-12f);
      float ib = 1.f / fmaxf(sqrtf(rnB[row]), 1e-12f);
      const unsigned short* pa = A + (size_t)row * PD;
      const unsigned short* pb = B + (size_t)row * PD;
      for (int cidx = threadIdx.x; cidx < PD; cidx += 256) {
        float d = bf2f(pa[cidx]) * ia - bf2f(pb[cidx]) * ib;
        s += d * d;
      }
    }
    s = blockReduce(s);
    if (threadIdx.x == 0) atomicAdd(acc, s * cZ);
  }
}

__global__ void k_final(const float* __restrict__ acc, float* __restrict__ out) {
  if (threadIdx.x == 0) out[0] = acc[0];
}

// ---------------- host ----------------
extern "C" void kernel_launch(void* const* d_in, const int* in_sizes, int n_in,
                              void* d_out, int out_size, void* d_ws, size_t ws_size,
                              hipStream_t stream) {
  const float* feats = (const float*)d_in[0];
  const int* labels = (const int*)d_in[1];
  const float* fc1 = (const float*)d_in[2];
  const float* fc2 = (const float*)d_in[3];
  const float* gamma = (const float*)d_in[4];
  const float* beta = (const float*)d_in[5];
  const float* proj = (const float*)d_in[6];
  float* out = (float*)d_out;

  char* w = (char*)d_ws;
  auto alloc = [&](size_t bytes) { char* p = w; w += (bytes + 255) & ~(size_t)255; return p; };
  float* bufA = (float*)alloc((size_t)NL * NROWS * DIM * 4);
  float* bufB = (float*)alloc((size_t)NL * NROWS * DIM * 4);
  unsigned short* Gpb = (unsigned short*)alloc((size_t)NL * NROWS * DIM * 2);
  unsigned short* actb = (unsigned short*)alloc((size_t)NL * NROWS * DIM * 2);
  unsigned short* W1b = (unsigned short*)alloc((size_t)NL * DIM * DIM * 2);
  unsigned short* W2b = (unsigned short*)alloc((size_t)NL * DIM * DIM * 2);
  unsigned short* Pjb = (unsigned short*)alloc((size_t)PD * DIM * 2);
  float* sim  = (float*)alloc((size_t)NL * NCLS * CAP * CAP * 4);
  float* S    = (float*)alloc((size_t)NL * NCLS * CAP * CAP * 4);
  unsigned short* Pb = (unsigned short*)alloc((size_t)NL * NROWS * PD * 2);
  float* invn = (float*)alloc((size_t)NL * NROWS * 4);
  float* dinv = (float*)alloc((size_t)NL * NCLS * CAP * 4);
  float* part = (float*)alloc((size_t)NL * PARTSZ * 4);
  float* bnsc = (float*)alloc((size_t)NL * 2 * DIM * 4);
  float* rnorm = (float*)alloc((size_t)NL * NROWS * 4);
  float* acc  = (float*)alloc(256);
  int* cnt  = (int*)alloc(NCLS * 4);
  int* offc = (int*)alloc((NCLS + 1) * 4);
  int* perm = (int*)alloc(NROWS * 4);
  int* clsp = (int*)alloc(NROWS * 4);
  int* t8   = (int*)alloc((size_t)NL * NROWS * 8 * 4);
  int* chunkCnt  = (int*)alloc(16 * NCLS * 4);
  int* chunkBase = (int*)alloc(16 * NCLS * 4);

  const float LAM_K = 64.f, LAM_Z = 16.f, SIGMA = 0.99f;
  const float cK = LAM_K / ((float)NROWS * (float)NROWS);
  const float cZ = LAM_Z / ((float)NROWS * (float)PD);
  const float cI = 1.f / ((float)NROWS * (float)NROWS);
  const long sAct = (long)NROWS * DIM;
  const long sW = (long)DIM * DIM;

  hipLaunchKernelGGL(k_hist, dim3(16), dim3(256), 0, stream, labels, chunkCnt);
  hipLaunchKernelGGL(k_scan, dim3(1), dim3(64), 0, stream, chunkCnt, cnt, offc, chunkBase, acc);
  hipLaunchKernelGGL(k_scatter, dim3(16), dim3(256), 0, stream, labels, chunkBase, perm, clsp);

  // fused prep (per-layer gather+bf16+invn), weight bf16 conversion, rnorm zero
  hipLaunchKernelGGL(k_prepw, dim3(NROWS, NL + 1), dim3(128), 0, stream, feats, perm, Gpb, invn,
                     (const float4*)fc1, (const float4*)fc2, (const float4*)proj,
                     (ushort4*)W1b, (ushort4*)W2b, (ushort4*)Pjb, rnorm);

  hipLaunchKernelGGL(k_sim, dim3(16, NCLS, NL), dim3(256), 0, stream, Gpb, invn, cnt, offc, sim);
  hipLaunchKernelGGL(k_topk, dim3(NROWS / 256, NL), dim3(256), 0, stream, sim, cnt, offc, clsp, t8);
  hipLaunchKernelGGL(k_buildS1, dim3(NCLS, CAP / 32, NL), dim3(256), 0, stream, sim, cnt, offc, t8, S, dinv);
  hipLaunchKernelGGL(k_buildS2, dim3(NCLS, CAP / 32, NL), dim3(256), 0, stream, S, dinv, cnt);

  // T1 = Gp @ w1^T (fp32 out)
  hipLaunchKernelGGL(k_gemm_bf16, dim3(NROWS / 128, DIM / 64, NL), dim3(256), 0, stream,
                     (const short*)Gpb, (const short*)W1b, bufA, (unsigned short*)nullptr, (float*)nullptr,
                     DIM, sAct, sW, (long)NROWS * DIM);
  // T2 = S @ T1 (+ fused BN column partial stats)
  hipLaunchKernelGGL(k_spmm32p, dim3(NCLS, DIM / 256, 4 * NL), dim3(256), 0, stream, S, bufA,
                     (const unsigned short*)nullptr, bufB, (unsigned short*)nullptr, part, cnt, offc);
  // BN finalize + relu -> bf16 T3
  hipLaunchKernelGGL(k_bnfin, dim3(DIM / 64, NL), dim3(64), 0, stream, part, gamma, beta, bnsc);
  hipLaunchKernelGGL(k_bnrelu, dim3(NROWS * DIM / 4 / 256, NL), dim3(256), 0, stream,
                     (const float4*)bufB, bnsc, (ushort4*)actb);
  // T4 = T3 @ w2^T (fp32 out)
  hipLaunchKernelGGL(k_gemm_bf16, dim3(NROWS / 128, DIM / 64, NL), dim3(256), 0, stream,
                     (const short*)actb, (const short*)W2b, bufB, (unsigned short*)nullptr, (float*)nullptr,
                     DIM, sAct, sW, (long)NROWS * DIM);
  // Z = S @ T4 + Gpb(bf16 residual) -> bf16 (actb)
  hipLaunchKernelGGL(k_spmm32p, dim3(NCLS, DIM / 256, 4 * NL), dim3(256), 0, stream, S, bufB,
                     Gpb, (float*)nullptr, actb, (float*)nullptr, cnt, offc);
  // P = Z @ proj^T (bf16 out, fused row-sumsq from fp32 acc into rnorm)
  hipLaunchKernelGGL(k_gemm_bf16, dim3(NROWS / 128, PD / 64, NL), dim3(256), 0, stream,
                     (const short*)actb, (const short*)Pjb, (float*)nullptr, Pb, rnorm,
                     PD, sAct, 0L, (long)NROWS * PD);

  // merged losses (P normalized on the fly)
  hipLaunchKernelGGL(k_loss, dim3(512, 5), dim3(256), 0, stream, S, Pb, rnorm, cnt, SIGMA, cK, cI, cZ, acc);

  hipLaunchKernelGGL(k_final, dim3(1), dim3(64), 0, stream, acc, out);
}